// Round 3
// baseline (574.185 us; speedup 1.0000x reference)
//
#include <hip/hip_runtime.h>

#define N_PTS 4096
#define ICP_STEPS 10
#define NBLK 256          // 1 block/CU
#define BS 512            // 8 waves/block; 2 queries per wave
#define NWAVE (BS / 64)
#define POWER_ITERS 24
#define NSUB 16           // arrival sub-counters (64B apart) to cut RMW contention
#define ASTRIDE 16        // ints between sub-counters

// ctrl layout (in ints):
//   arrive[ICP_STEPS][NSUB*ASTRIDE]   (release fetch_add targets)
//   flag[ICP_STEPS*16]                (per-step publish flag, 64B apart)
//   rt[ICP_STEPS][16]                 (published R|t, as floats)
#define ARRIVE_OFF 0
#define FLAG_OFF   (ICP_STEPS * NSUB * ASTRIDE)            // 2560
#define RT_OFF     (FLAG_OFF + ICP_STEPS * 16)             // 2720
#define CTRL_INTS  (RT_OFF + ICP_STEPS * 16)               // 2880 ints = 11520 B
#define PART_OFF_B 12288                                    // byte offset of partials in ws

__global__ __launch_bounds__(BS, 2) void icp_pk(const float* __restrict__ p1,
                                                const float* __restrict__ p2,
                                                int* __restrict__ ctrl,
                                                float* __restrict__ partials,  // [2][NBLK][16]
                                                float* __restrict__ out) {
    __shared__ __align__(16) float4 sp2[N_PTS];   // 64 KB {x,y,z,|p|^2}
    __shared__ float wred[NWAVE][16];
    __shared__ float rred[16][33];
    __shared__ float sol[16];
    __shared__ float bl[12];

    const int tid = threadIdx.x;
    const int bid = blockIdx.x;
    const int wave = tid >> 6;
    const int lane = tid & 63;

    int* arrive = ctrl + ARRIVE_OFF;
    int* flag = ctrl + FLAG_OFF;
    float* rt = (float*)(ctrl + RT_OFF);

    // ---- stage p2 -> LDS once ----
    for (int p = tid; p < N_PTS; p += BS) {
        const float x = p2[3 * p + 0];
        const float y = p2[3 * p + 1];
        const float z = p2[3 * p + 2];
        sp2[p] = make_float4(x, y, z, x * x + y * y + z * z);
    }

    // ---- owned queries: 16/block, 2/wave, live in registers across all steps ----
    const int q0 = bid * 16 + wave * 2;
    const int q1 = q0 + 1;
    float q0x = p1[3 * q0 + 0], q0y = p1[3 * q0 + 1], q0z = p1[3 * q0 + 2];
    float q1x = p1[3 * q1 + 0], q1y = p1[3 * q1 + 1], q1z = p1[3 * q1 + 2];

    // composed transform (solver block only uses these)
    float cqw = 1.0f, cqx = 0.0f, cqy = 0.0f, cqz = 0.0f;
    float ctx = 0.0f, cty = 0.0f, ctz = 0.0f;

    __syncthreads();

    for (int s = 0; s < ICP_STEPS; ++s) {
        const bool last = (s == ICP_STEPS - 1);

        // ---- 1-NN: argmin_j (|p_j|^2 - 2 q.p_j), 3 FMA per (q,cand) ----
        const float a0x = -2.0f * q0x, a0y = -2.0f * q0y, a0z = -2.0f * q0z;
        const float a1x = -2.0f * q1x, a1y = -2.0f * q1y, a1z = -2.0f * q1z;
        float b0 = 3.4e38f, b1 = 3.4e38f;
        int i0 = 0, i1 = 0;
        #pragma unroll 8
        for (int k = 0; k < N_PTS / 64; ++k) {
            const int j = lane + (k << 6);
            const float4 P = sp2[j];
            float s0 = __builtin_fmaf(P.z, a0z, P.w);
            s0 = __builtin_fmaf(P.y, a0y, s0);
            s0 = __builtin_fmaf(P.x, a0x, s0);
            float s1 = __builtin_fmaf(P.z, a1z, P.w);
            s1 = __builtin_fmaf(P.y, a1y, s1);
            s1 = __builtin_fmaf(P.x, a1x, s1);
            if (s0 < b0) { b0 = s0; i0 = j; }
            if (s1 < b1) { b1 = s1; i1 = j; }
        }
        for (int off = 32; off; off >>= 1) {
            const float o0 = __shfl_xor(b0, off, 64);
            const int oj0 = __shfl_xor(i0, off, 64);
            if (o0 < b0 || (o0 == b0 && oj0 < i0)) { b0 = o0; i0 = oj0; }
            const float o1 = __shfl_xor(b1, off, 64);
            const int oj1 = __shfl_xor(i1, off, 64);
            if (o1 < b1 || (o1 == b1 && oj1 < i1)) { b1 = o1; i1 = oj1; }
        }
        const float4 M0 = sp2[i0];
        const float4 M1 = sp2[i1];

        // ---- per-wave Kabsch partials -> one 16-float row per block ----
        __syncthreads();
        if (lane == 0) {
            float* r = wred[wave];
            r[0]  = q0x + q1x;   r[1]  = q0y + q1y;   r[2]  = q0z + q1z;
            r[3]  = M0.x + M1.x; r[4]  = M0.y + M1.y; r[5]  = M0.z + M1.z;
            r[6]  = q0x * M0.x + q1x * M1.x;
            r[7]  = q0x * M0.y + q1x * M1.y;
            r[8]  = q0x * M0.z + q1x * M1.z;
            r[9]  = q0y * M0.x + q1y * M1.x;
            r[10] = q0y * M0.y + q1y * M1.y;
            r[11] = q0y * M0.z + q1y * M1.z;
            r[12] = q0z * M0.x + q1z * M1.x;
            r[13] = q0z * M0.y + q1z * M1.y;
            r[14] = q0z * M0.z + q1z * M1.z;
            r[15] = 0.0f;
        }
        __syncthreads();
        if (tid < 16) {
            float acc = 0.0f;
            #pragma unroll
            for (int w2 = 0; w2 < NWAVE; ++w2) acc += wred[w2][tid];
            partials[(((size_t)(s & 1)) * NBLK + bid) * 16 + tid] = acc;
        }
        __syncthreads();  // compiler emits vmcnt(0) before barrier: row is in L2

        if (tid == 0) {
            // release: writes back this XCD's L2 so the row is globally visible
            __hip_atomic_fetch_add(&arrive[s * NSUB * ASTRIDE + (bid & (NSUB - 1)) * ASTRIDE],
                                   1, __ATOMIC_RELEASE, __HIP_MEMORY_SCOPE_AGENT);
        }

        if (bid == 0) {
            // ================= solver block =================
            if (tid == 0) {
                int sum;
                do {
                    sum = 0;
                    #pragma unroll
                    for (int i = 0; i < NSUB; ++i)
                        sum += __hip_atomic_load(&arrive[s * NSUB * ASTRIDE + i * ASTRIDE],
                                                 __ATOMIC_ACQUIRE, __HIP_MEMORY_SCOPE_AGENT);
                    if (sum < NBLK) __builtin_amdgcn_s_sleep(1);
                } while (sum < NBLK);
            }
            __syncthreads();

            // reduce NBLK rows; relaxed agent atomic loads read the coherence point
            {
                const int v = tid & 15;
                const int g = tid >> 4;  // 0..31
                const float* base = partials + ((size_t)(s & 1)) * NBLK * 16;
                float acc = 0.0f;
                #pragma unroll
                for (int r = 0; r < NBLK / 32; ++r) {
                    const int row = g + r * 32;
                    acc += __hip_atomic_load((const float*)&base[row * 16 + v],
                                             __ATOMIC_RELAXED, __HIP_MEMORY_SCOPE_AGENT);
                }
                rred[v][g] = acc;
            }
            __syncthreads();
            if (tid < 16) {
                float sm = 0.0f;
                #pragma unroll
                for (int g2 = 0; g2 < 32; ++g2) sm += rred[tid][g2];
                sol[tid] = sm;
            }
            __syncthreads();

            const float S1x = sol[0], S1y = sol[1], S1z = sol[2];
            const float S2x = sol[3], S2y = sol[4], S2z = sol[5];
            const float Mxx = sol[6], Mxy = sol[7], Mxz = sol[8];
            const float Myx = sol[9], Myy = sol[10], Myz = sol[11];
            const float Mzx = sol[12], Mzy = sol[13], Mzz = sol[14];

            const float invN = 1.0f / (float)N_PTS;
            const float c1x = S1x * invN, c1y = S1y * invN, c1z = S1z * invN;
            const float c2x = S2x * invN, c2y = S2y * invN, c2z = S2z * invN;

            const float Sxx = Mxx - S1x * S2x * invN;
            const float Sxy = Mxy - S1x * S2y * invN;
            const float Sxz = Mxz - S1x * S2z * invN;
            const float Syx = Myx - S1y * S2x * invN;
            const float Syy = Myy - S1y * S2y * invN;
            const float Syz = Myz - S1y * S2z * invN;
            const float Szx = Mzx - S1z * S2x * invN;
            const float Szy = Mzy - S1z * S2y * invN;
            const float Szz = Mzz - S1z * S2z * invN;

            const float N00 = Sxx + Syy + Szz;
            const float N01 = Syz - Szy;
            const float N02 = Szx - Sxz;
            const float N03 = Sxy - Syx;
            const float N11 = Sxx - Syy - Szz;
            const float N12 = Sxy + Syx;
            const float N13 = Szx + Sxz;
            const float N22 = -Sxx + Syy - Szz;
            const float N23 = Syz + Szy;
            const float N33 = -Sxx - Syy + Szz;

            const float fro = sqrtf(N00 * N00 + N11 * N11 + N22 * N22 + N33 * N33 +
                                    2.0f * (N01 * N01 + N02 * N02 + N03 * N03 +
                                            N12 * N12 + N13 * N13 + N23 * N23));
            const float sg = fro + 1e-20f;

            float w = 1.0f, x = 0.0f, y = 0.0f, z = 0.0f;
            for (int it = 0; it < POWER_ITERS; ++it) {
                const float r0 = N00 * w + N01 * x + N02 * y + N03 * z + sg * w;
                const float r1 = N01 * w + N11 * x + N12 * y + N13 * z + sg * x;
                const float r2 = N02 * w + N12 * x + N22 * y + N23 * z + sg * y;
                const float r3 = N03 * w + N13 * x + N23 * y + N33 * z + sg * z;
                const float inv = rsqrtf(r0 * r0 + r1 * r1 + r2 * r2 + r3 * r3 + 1e-30f);
                w = r0 * inv; x = r1 * inv; y = r2 * inv; z = r3 * inv;
            }

            const float xx = x * x, yy = y * y, zz = z * z;
            const float xy = x * y, xz = x * z, yz = y * z;
            const float wx = w * x, wy = w * y, wz = w * z;
            const float R00 = 1.0f - 2.0f * (yy + zz), R01 = 2.0f * (xy - wz), R02 = 2.0f * (xz + wy);
            const float R10 = 2.0f * (xy + wz), R11 = 1.0f - 2.0f * (xx + zz), R12 = 2.0f * (yz - wx);
            const float R20 = 2.0f * (xz - wy), R21 = 2.0f * (yz + wx), R22 = 1.0f - 2.0f * (xx + yy);

            const float tx = c2x - (R00 * c1x + R01 * c1y + R02 * c1z);
            const float ty = c2y - (R10 * c1x + R11 * c1y + R12 * c1z);
            const float tz = c2z - (R20 * c1x + R21 * c1y + R22 * c1z);

            // compose totals
            {
                const float nw = w * cqw - x * cqx - y * cqy - z * cqz;
                const float nx = w * cqx + x * cqw + y * cqz - z * cqy;
                const float ny = w * cqy - x * cqz + y * cqw + z * cqx;
                const float nz = w * cqz + x * cqy - y * cqx + z * cqw;
                cqw = nw; cqx = nx; cqy = ny; cqz = nz;
                const float ntx = R00 * ctx + R01 * cty + R02 * ctz + tx;
                const float nty = R10 * ctx + R11 * cty + R12 * ctz + ty;
                const float ntz = R20 * ctx + R21 * cty + R22 * ctz + tz;
                ctx = ntx; cty = nty; ctz = ntz;
            }

            if (!last) {
                if (tid == 0) {
                    float rv[12] = {R00, R01, R02, R10, R11, R12, R20, R21, R22, tx, ty, tz};
                    #pragma unroll
                    for (int i = 0; i < 12; ++i)
                        __hip_atomic_store(&rt[s * 16 + i], rv[i],
                                           __ATOMIC_RELAXED, __HIP_MEMORY_SCOPE_AGENT);
                    __hip_atomic_store(&flag[s * 16], 1,
                                       __ATOMIC_RELEASE, __HIP_MEMORY_SCOPE_AGENT);
                }
                // transform owned queries
                const float nx0 = R00 * q0x + R01 * q0y + R02 * q0z + tx;
                const float ny0 = R10 * q0x + R11 * q0y + R12 * q0z + ty;
                const float nz0 = R20 * q0x + R21 * q0y + R22 * q0z + tz;
                const float nx1 = R00 * q1x + R01 * q1y + R02 * q1z + tx;
                const float ny1 = R10 * q1x + R11 * q1y + R12 * q1z + ty;
                const float nz1 = R20 * q1x + R21 * q1y + R22 * q1z + tz;
                q0x = nx0; q0y = ny0; q0z = nz0;
                q1x = nx1; q1y = ny1; q1z = nz1;
            } else if (tid == 0) {
                // final Kabsch(p1, pc) == composed transform (H = C*Rc^T, C SPD)
                const float fxx = cqx * cqx, fyy = cqy * cqy, fzz = cqz * cqz;
                const float fxy = cqx * cqy, fxz = cqx * cqz, fyz = cqy * cqz;
                const float fwx = cqw * cqx, fwy = cqw * cqy, fwz = cqw * cqz;
                out[0]  = 1.0f - 2.0f * (fyy + fzz);
                out[1]  = 2.0f * (fxy - fwz);
                out[2]  = 2.0f * (fxz + fwy);
                out[3]  = ctx;
                out[4]  = 2.0f * (fxy + fwz);
                out[5]  = 1.0f - 2.0f * (fxx + fzz);
                out[6]  = 2.0f * (fyz - fwx);
                out[7]  = cty;
                out[8]  = 2.0f * (fxz - fwy);
                out[9]  = 2.0f * (fyz + fwx);
                out[10] = 1.0f - 2.0f * (fxx + fyy);
                out[11] = ctz;
            }
        } else if (!last) {
            // ================= spinner blocks =================
            if (tid == 0) {
                while (__hip_atomic_load(&flag[s * 16], __ATOMIC_ACQUIRE,
                                         __HIP_MEMORY_SCOPE_AGENT) == 0) {
                    __builtin_amdgcn_s_sleep(1);
                }
                #pragma unroll
                for (int i = 0; i < 12; ++i)
                    bl[i] = __hip_atomic_load(&rt[s * 16 + i], __ATOMIC_RELAXED,
                                              __HIP_MEMORY_SCOPE_AGENT);
            }
            __syncthreads();
            const float R00 = bl[0], R01 = bl[1], R02 = bl[2];
            const float R10 = bl[3], R11 = bl[4], R12 = bl[5];
            const float R20 = bl[6], R21 = bl[7], R22 = bl[8];
            const float tx = bl[9], ty = bl[10], tz = bl[11];
            const float nx0 = R00 * q0x + R01 * q0y + R02 * q0z + tx;
            const float ny0 = R10 * q0x + R11 * q0y + R12 * q0z + ty;
            const float nz0 = R20 * q0x + R21 * q0y + R22 * q0z + tz;
            const float nx1 = R00 * q1x + R01 * q1y + R02 * q1z + tx;
            const float ny1 = R10 * q1x + R11 * q1y + R12 * q1z + ty;
            const float nz1 = R20 * q1x + R21 * q1y + R22 * q1z + tz;
            q0x = nx0; q0y = ny0; q0z = nz0;
            q1x = nx1; q1y = ny1; q1z = nz1;
        }
        // no further sync needed: partials double-buffer + per-step slots bound skew to 1
    }
}

extern "C" void kernel_launch(void* const* d_in, const int* in_sizes, int n_in,
                              void* d_out, int out_size, void* d_ws, size_t ws_size,
                              hipStream_t stream) {
    const float* p1 = (const float*)d_in[0];
    const float* p2 = (const float*)d_in[1];
    float* out = (float*)d_out;

    int* ctrl = (int*)d_ws;
    float* partials = (float*)((char*)d_ws + PART_OFF_B);  // [2][NBLK][16] floats = 32 KB

    // zero the control region (arrive counters + flags + rt slots)
    hipMemsetAsync(ctrl, 0, CTRL_INTS * sizeof(int), stream);

    void* args[] = {(void*)&p1, (void*)&p2, (void*)&ctrl, (void*)&partials, (void*)&out};
    hipLaunchCooperativeKernel((const void*)icp_pk, dim3(NBLK), dim3(BS), args, 0, stream);
}

// Round 4
// 249.754 us; speedup vs baseline: 2.2990x; 2.2990x over previous
//
#include <hip/hip_runtime.h>

#define N_PTS 4096
#define ICP_STEPS 10
#define NBLK 256          // 1 block/CU (cooperative launch guarantees co-residency)
#define BS 512            // 8 waves/block; 2 queries per wave -> 16 queries/block
#define NWAVE (BS / 64)
#define POWER_ITERS 24

// All cross-block communication via RELAXED agent-scope RMW atomics (coherence
// point, no L2 writeback/invalidate). Ordering between data-RMWs and the
// signal-RMW is enforced with s_waitcnt vmcnt(0).
//
// ws layout (4-byte elems):
//   acc : [ICP_STEPS][16][8]   floats  (partial sums, 8 spread copies)   off 0
//   cnt : [ICP_STEPS][8][16]   ints    (8 arrival sub-counters, 64B apart) off 1280
//   rt  : [ICP_STEPS][8][12]   floats  (published R|t, 8 replicas)       off 2560
//   flag: [ICP_STEPS][16][16]  ints    (publish flag, 16 replicas)       off 3520
#define ACC_OFF  0
#define CNT_OFF  1280
#define RT_OFF   2560
#define FLAG_OFF 3520
#define CTRL_ELEMS 6080   // * 4 B = 24320 B

#define WAIT_VM0() __builtin_amdgcn_s_waitcnt(0x0f70)  // vmcnt(0), ignore exp/lgkm

__device__ __forceinline__ float afaddf(float* p, float v) {
    return __hip_atomic_fetch_add(p, v, __ATOMIC_RELAXED, __HIP_MEMORY_SCOPE_AGENT);
}
__device__ __forceinline__ int afaddi(int* p, int v) {
    return __hip_atomic_fetch_add(p, v, __ATOMIC_RELAXED, __HIP_MEMORY_SCOPE_AGENT);
}
__device__ __forceinline__ float aloadf(float* p) {   // RMW-read: always coherent
    return __hip_atomic_fetch_add(p, 0.0f, __ATOMIC_RELAXED, __HIP_MEMORY_SCOPE_AGENT);
}
__device__ __forceinline__ int aloadi(int* p) {
    return __hip_atomic_fetch_add(p, 0, __ATOMIC_RELAXED, __HIP_MEMORY_SCOPE_AGENT);
}

__global__ __launch_bounds__(BS, 2) void icp_pk(const float* __restrict__ p1,
                                                const float* __restrict__ p2,
                                                int* __restrict__ ctrl,
                                                float* __restrict__ out) {
    __shared__ __align__(16) float4 sp2[N_PTS];   // 64 KB {x,y,z,|p|^2}
    __shared__ float wred[NWAVE][16];
    __shared__ float rr[128];
    __shared__ float sol[16];
    __shared__ float bl[12];

    const int tid = threadIdx.x;
    const int bid = blockIdx.x;
    const int wave = tid >> 6;
    const int lane = tid & 63;

    float* acc = (float*)(ctrl + ACC_OFF);
    int* cnt = ctrl + CNT_OFF;
    float* rt = (float*)(ctrl + RT_OFF);
    int* flag = ctrl + FLAG_OFF;

    // ---- stage p2 -> LDS once ----
    for (int p = tid; p < N_PTS; p += BS) {
        const float x = p2[3 * p + 0];
        const float y = p2[3 * p + 1];
        const float z = p2[3 * p + 2];
        sp2[p] = make_float4(x, y, z, x * x + y * y + z * z);
    }

    // ---- owned queries: 16/block, 2/wave, registers across all steps ----
    const int q0 = bid * 16 + wave * 2;
    const int q1 = q0 + 1;
    float q0x = p1[3 * q0 + 0], q0y = p1[3 * q0 + 1], q0z = p1[3 * q0 + 2];
    float q1x = p1[3 * q1 + 0], q1y = p1[3 * q1 + 1], q1z = p1[3 * q1 + 2];

    // composed transform (meaningful in solver block only)
    float cqw = 1.0f, cqx = 0.0f, cqy = 0.0f, cqz = 0.0f;
    float ctx = 0.0f, cty = 0.0f, ctz = 0.0f;

    __syncthreads();

    for (int s = 0; s < ICP_STEPS; ++s) {
        const bool last = (s == ICP_STEPS - 1);

        // ---- 1-NN: argmin_j (|p_j|^2 - 2 q.p_j) ----
        const float a0x = -2.0f * q0x, a0y = -2.0f * q0y, a0z = -2.0f * q0z;
        const float a1x = -2.0f * q1x, a1y = -2.0f * q1y, a1z = -2.0f * q1z;
        float b0 = 3.4e38f, b1 = 3.4e38f;
        int i0 = 0, i1 = 0;
        #pragma unroll 8
        for (int k = 0; k < N_PTS / 64; ++k) {
            const int j = lane + (k << 6);
            const float4 P = sp2[j];
            float s0 = __builtin_fmaf(P.z, a0z, P.w);
            s0 = __builtin_fmaf(P.y, a0y, s0);
            s0 = __builtin_fmaf(P.x, a0x, s0);
            float s1 = __builtin_fmaf(P.z, a1z, P.w);
            s1 = __builtin_fmaf(P.y, a1y, s1);
            s1 = __builtin_fmaf(P.x, a1x, s1);
            if (s0 < b0) { b0 = s0; i0 = j; }
            if (s1 < b1) { b1 = s1; i1 = j; }
        }
        for (int off = 32; off; off >>= 1) {
            const float o0 = __shfl_xor(b0, off, 64);
            const int oj0 = __shfl_xor(i0, off, 64);
            if (o0 < b0 || (o0 == b0 && oj0 < i0)) { b0 = o0; i0 = oj0; }
            const float o1 = __shfl_xor(b1, off, 64);
            const int oj1 = __shfl_xor(i1, off, 64);
            if (o1 < b1 || (o1 == b1 && oj1 < i1)) { b1 = o1; i1 = oj1; }
        }
        const float4 M0 = sp2[i0];
        const float4 M1 = sp2[i1];

        // ---- per-wave Kabsch partials -> block row of 16 ----
        __syncthreads();
        if (lane == 0) {
            float* r = wred[wave];
            r[0]  = q0x + q1x;   r[1]  = q0y + q1y;   r[2]  = q0z + q1z;
            r[3]  = M0.x + M1.x; r[4]  = M0.y + M1.y; r[5]  = M0.z + M1.z;
            r[6]  = q0x * M0.x + q1x * M1.x;
            r[7]  = q0x * M0.y + q1x * M1.y;
            r[8]  = q0x * M0.z + q1x * M1.z;
            r[9]  = q0y * M0.x + q1y * M1.x;
            r[10] = q0y * M0.y + q1y * M1.y;
            r[11] = q0y * M0.z + q1y * M1.z;
            r[12] = q0z * M0.x + q1z * M1.x;
            r[13] = q0z * M0.y + q1z * M1.y;
            r[14] = q0z * M0.z + q1z * M1.z;
            r[15] = 0.0f;
        }
        __syncthreads();
        if (tid < 16) {
            float v = 0.0f;
            #pragma unroll
            for (int w2 = 0; w2 < NWAVE; ++w2) v += wred[w2][tid];
            afaddf(&acc[(s * 16 + tid) * 8 + (bid & 7)], v);   // relaxed RMW -> IF
        }
        WAIT_VM0();            // wave 0: acc adds committed at coherence point
        if (tid == 0) afaddi(&cnt[(s * 8 + (bid & 7)) * 16], 1);

        if (bid == 0) {
            // ================= solver =================
            if (tid == 0) {
                int sum;
                do {
                    sum = 0;
                    #pragma unroll
                    for (int i = 0; i < 8; ++i) sum += aloadi(&cnt[(s * 8 + i) * 16]);
                    if (sum < NBLK) __builtin_amdgcn_s_sleep(4);
                } while (sum < NBLK);
            }
            __syncthreads();
            if (tid < 128) rr[tid] = aloadf(&acc[s * 128 + tid]);  // [i][c] i=tid>>3,c=tid&7
            __syncthreads();
            if (tid < 16) {
                float sm = 0.0f;
                #pragma unroll
                for (int c = 0; c < 8; ++c) sm += rr[tid * 8 + c];
                sol[tid] = sm;
            }
            __syncthreads();

            const float S1x = sol[0], S1y = sol[1], S1z = sol[2];
            const float S2x = sol[3], S2y = sol[4], S2z = sol[5];
            const float Mxx = sol[6], Mxy = sol[7], Mxz = sol[8];
            const float Myx = sol[9], Myy = sol[10], Myz = sol[11];
            const float Mzx = sol[12], Mzy = sol[13], Mzz = sol[14];

            const float invN = 1.0f / (float)N_PTS;
            const float c1x = S1x * invN, c1y = S1y * invN, c1z = S1z * invN;
            const float c2x = S2x * invN, c2y = S2y * invN, c2z = S2z * invN;

            const float Sxx = Mxx - S1x * S2x * invN;
            const float Sxy = Mxy - S1x * S2y * invN;
            const float Sxz = Mxz - S1x * S2z * invN;
            const float Syx = Myx - S1y * S2x * invN;
            const float Syy = Myy - S1y * S2y * invN;
            const float Syz = Myz - S1y * S2z * invN;
            const float Szx = Mzx - S1z * S2x * invN;
            const float Szy = Mzy - S1z * S2y * invN;
            const float Szz = Mzz - S1z * S2z * invN;

            const float N00 = Sxx + Syy + Szz;
            const float N01 = Syz - Szy;
            const float N02 = Szx - Sxz;
            const float N03 = Sxy - Syx;
            const float N11 = Sxx - Syy - Szz;
            const float N12 = Sxy + Syx;
            const float N13 = Szx + Sxz;
            const float N22 = -Sxx + Syy - Szz;
            const float N23 = Syz + Szy;
            const float N33 = -Sxx - Syy + Szz;

            const float fro = sqrtf(N00 * N00 + N11 * N11 + N22 * N22 + N33 * N33 +
                                    2.0f * (N01 * N01 + N02 * N02 + N03 * N03 +
                                            N12 * N12 + N13 * N13 + N23 * N23));
            const float sg = fro + 1e-20f;

            float w = 1.0f, x = 0.0f, y = 0.0f, z = 0.0f;
            for (int it = 0; it < POWER_ITERS; ++it) {
                const float r0 = N00 * w + N01 * x + N02 * y + N03 * z + sg * w;
                const float r1 = N01 * w + N11 * x + N12 * y + N13 * z + sg * x;
                const float r2 = N02 * w + N12 * x + N22 * y + N23 * z + sg * y;
                const float r3 = N03 * w + N13 * x + N23 * y + N33 * z + sg * z;
                const float inv = rsqrtf(r0 * r0 + r1 * r1 + r2 * r2 + r3 * r3 + 1e-30f);
                w = r0 * inv; x = r1 * inv; y = r2 * inv; z = r3 * inv;
            }

            const float xx = x * x, yy = y * y, zz = z * z;
            const float xy = x * y, xz = x * z, yz = y * z;
            const float wx = w * x, wy = w * y, wz = w * z;
            const float R00 = 1.0f - 2.0f * (yy + zz), R01 = 2.0f * (xy - wz), R02 = 2.0f * (xz + wy);
            const float R10 = 2.0f * (xy + wz), R11 = 1.0f - 2.0f * (xx + zz), R12 = 2.0f * (yz - wx);
            const float R20 = 2.0f * (xz - wy), R21 = 2.0f * (yz + wx), R22 = 1.0f - 2.0f * (xx + yy);

            const float tx = c2x - (R00 * c1x + R01 * c1y + R02 * c1z);
            const float ty = c2y - (R10 * c1x + R11 * c1y + R12 * c1z);
            const float tz = c2z - (R20 * c1x + R21 * c1y + R22 * c1z);

            // compose totals
            {
                const float nw = w * cqw - x * cqx - y * cqy - z * cqz;
                const float nx = w * cqx + x * cqw + y * cqz - z * cqy;
                const float ny = w * cqy - x * cqz + y * cqw + z * cqx;
                const float nz = w * cqz + x * cqy - y * cqx + z * cqw;
                cqw = nw; cqx = nx; cqy = ny; cqz = nz;
                const float ntx = R00 * ctx + R01 * cty + R02 * ctz + tx;
                const float nty = R10 * ctx + R11 * cty + R12 * ctz + ty;
                const float ntz = R20 * ctx + R21 * cty + R22 * ctz + tz;
                ctx = ntx; cty = nty; ctz = ntz;
            }

            if (!last) {
                if (tid == 0) {
                    bl[0] = R00; bl[1] = R01; bl[2] = R02;
                    bl[3] = R10; bl[4] = R11; bl[5] = R12;
                    bl[6] = R20; bl[7] = R21; bl[8] = R22;
                    bl[9] = tx;  bl[10] = ty; bl[11] = tz;
                }
                __syncthreads();
                if (tid < 96) {                      // 8 replicas x 12 values
                    const int cp = tid / 12, i = tid - cp * 12;
                    afaddf(&rt[(s * 8 + cp) * 12 + i], bl[i]);
                }
                WAIT_VM0();                          // waves 0-1: rt committed
                __syncthreads();                     // both waves past their waitcnt
                if (tid < 16) afaddi(&flag[(s * 16 + tid) * 16], 1);

                const float nx0 = R00 * q0x + R01 * q0y + R02 * q0z + tx;
                const float ny0 = R10 * q0x + R11 * q0y + R12 * q0z + ty;
                const float nz0 = R20 * q0x + R21 * q0y + R22 * q0z + tz;
                const float nx1 = R00 * q1x + R01 * q1y + R02 * q1z + tx;
                const float ny1 = R10 * q1x + R11 * q1y + R12 * q1z + ty;
                const float nz1 = R20 * q1x + R21 * q1y + R22 * q1z + tz;
                q0x = nx0; q0y = ny0; q0z = nz0;
                q1x = nx1; q1y = ny1; q1z = nz1;
            } else if (tid == 0) {
                // final Kabsch(p1, pc) == composed transform
                const float fxx = cqx * cqx, fyy = cqy * cqy, fzz = cqz * cqz;
                const float fxy = cqx * cqy, fxz = cqx * cqz, fyz = cqy * cqz;
                const float fwx = cqw * cqx, fwy = cqw * cqy, fwz = cqw * cqz;
                out[0]  = 1.0f - 2.0f * (fyy + fzz);
                out[1]  = 2.0f * (fxy - fwz);
                out[2]  = 2.0f * (fxz + fwy);
                out[3]  = ctx;
                out[4]  = 2.0f * (fxy + fwz);
                out[5]  = 1.0f - 2.0f * (fxx + fzz);
                out[6]  = 2.0f * (fyz - fwx);
                out[7]  = cty;
                out[8]  = 2.0f * (fxz - fwy);
                out[9]  = 2.0f * (fyz + fwx);
                out[10] = 1.0f - 2.0f * (fxx + fyy);
                out[11] = ctz;
            }
        } else if (!last) {
            // ================= spinners =================
            if (tid == 0) {
                while (aloadi(&flag[(s * 16 + (bid & 15)) * 16]) == 0) {
                    __builtin_amdgcn_s_sleep(4);
                }
            }
            __syncthreads();
            if (tid < 12) bl[tid] = aloadf(&rt[(s * 8 + (bid & 7)) * 12 + tid]);
            __syncthreads();
            const float R00 = bl[0], R01 = bl[1], R02 = bl[2];
            const float R10 = bl[3], R11 = bl[4], R12 = bl[5];
            const float R20 = bl[6], R21 = bl[7], R22 = bl[8];
            const float tx = bl[9], ty = bl[10], tz = bl[11];
            const float nx0 = R00 * q0x + R01 * q0y + R02 * q0z + tx;
            const float ny0 = R10 * q0x + R11 * q0y + R12 * q0z + ty;
            const float nz0 = R20 * q0x + R21 * q0y + R22 * q0z + tz;
            const float nx1 = R00 * q1x + R01 * q1y + R02 * q1z + tx;
            const float ny1 = R10 * q1x + R11 * q1y + R12 * q1z + ty;
            const float nz1 = R20 * q1x + R21 * q1y + R22 * q1z + tz;
            q0x = nx0; q0y = ny0; q0z = nz0;
            q1x = nx1; q1y = ny1; q1z = nz1;
        }
        __syncthreads();
    }
}

extern "C" void kernel_launch(void* const* d_in, const int* in_sizes, int n_in,
                              void* d_out, int out_size, void* d_ws, size_t ws_size,
                              hipStream_t stream) {
    const float* p1 = (const float*)d_in[0];
    const float* p2 = (const float*)d_in[1];
    float* out = (float*)d_out;
    int* ctrl = (int*)d_ws;

    hipMemsetAsync(ctrl, 0, CTRL_ELEMS * sizeof(int), stream);

    void* args[] = {(void*)&p1, (void*)&p2, (void*)&ctrl, (void*)&out};
    hipLaunchCooperativeKernel((const void*)icp_pk, dim3(NBLK), dim3(BS), args, 0, stream);
}

// Round 5
// 238.515 us; speedup vs baseline: 2.4073x; 1.0471x over previous
//
#include <hip/hip_runtime.h>

#define N_PTS 4096
#define ICP_STEPS 10
#define NBLK 256          // 1 block/CU (cooperative launch guarantees co-residency)
#define BS 256            // 4 waves/block; 4 queries per wave -> 16 queries/block
#define NWAVE (BS / 64)
#define QPW 4             // queries per wave
#define POWER_ITERS 16

// All cross-block communication via RELAXED agent-scope RMW atomics (coherence
// point, no L2 wb/inv). Ordering data-RMW -> signal-RMW via s_waitcnt vmcnt(0).
//
// ws layout (4-byte elems), zeroed by hipMemsetAsync before launch:
//   acc : [ICP_STEPS][16][8]    floats (partial sums, 8 spread copies)     off 0
//   cnt : [ICP_STEPS][8][16]    ints   (8 arrival sub-counters, 64B apart) off 1280
//   rt  : [ICP_STEPS][16][12]   floats (published R|t, 16 replicas)        off 2560
//   flag: [ICP_STEPS][16][16]   ints   (publish flag, 16 replicas)         off 4480
#define ACC_OFF  0
#define CNT_OFF  1280
#define RT_OFF   2560
#define FLAG_OFF 4480
#define CTRL_ELEMS 7040   // * 4 B = 28160 B

#define WAIT_VM0() __builtin_amdgcn_s_waitcnt(0x0f70)  // vmcnt(0)

__device__ __forceinline__ float afaddf(float* p, float v) {
    return __hip_atomic_fetch_add(p, v, __ATOMIC_RELAXED, __HIP_MEMORY_SCOPE_AGENT);
}
__device__ __forceinline__ int afaddi(int* p, int v) {
    return __hip_atomic_fetch_add(p, v, __ATOMIC_RELAXED, __HIP_MEMORY_SCOPE_AGENT);
}
__device__ __forceinline__ float aloadf(float* p) {   // RMW-read: always coherent
    return __hip_atomic_fetch_add(p, 0.0f, __ATOMIC_RELAXED, __HIP_MEMORY_SCOPE_AGENT);
}
__device__ __forceinline__ int aloadi(int* p) {
    return __hip_atomic_fetch_add(p, 0, __ATOMIC_RELAXED, __HIP_MEMORY_SCOPE_AGENT);
}

__global__ __launch_bounds__(BS, 1) void icp_pk(const float* __restrict__ p1,
                                                const float* __restrict__ p2,
                                                int* __restrict__ ctrl,
                                                float* __restrict__ out) {
    __shared__ __align__(16) float4 sp2[N_PTS];   // 64 KB {x,y,z,|p|^2}
    __shared__ float wred[NWAVE][16];
    __shared__ float rr[128];
    __shared__ float sol[16];
    __shared__ float bl[12];

    const int tid = threadIdx.x;
    const int bid = blockIdx.x;
    const int wave = tid >> 6;
    const int lane = tid & 63;

    float* acc = (float*)(ctrl + ACC_OFF);
    int* cnt = ctrl + CNT_OFF;
    float* rt = (float*)(ctrl + RT_OFF);
    int* flag = ctrl + FLAG_OFF;

    // ---- stage p2 -> LDS once ----
    for (int p = tid; p < N_PTS; p += BS) {
        const float x = p2[3 * p + 0];
        const float y = p2[3 * p + 1];
        const float z = p2[3 * p + 2];
        sp2[p] = make_float4(x, y, z, x * x + y * y + z * z);
    }

    // ---- owned queries: 16/block, 4/wave (every lane tracks the same 4) ----
    const int qb = bid * 16 + wave * QPW;
    float qx[QPW], qy[QPW], qz[QPW];
    #pragma unroll
    for (int j = 0; j < QPW; ++j) {
        qx[j] = p1[3 * (qb + j) + 0];
        qy[j] = p1[3 * (qb + j) + 1];
        qz[j] = p1[3 * (qb + j) + 2];
    }

    // composed transform (meaningful in solver block only)
    float cqw = 1.0f, cqx = 0.0f, cqy = 0.0f, cqz = 0.0f;
    float ctx = 0.0f, cty = 0.0f, ctz = 0.0f;

    __syncthreads();

    for (int s = 0; s < ICP_STEPS; ++s) {
        const bool last = (s == ICP_STEPS - 1);

        // ---- 1-NN for 4 queries: argmin_j (|p_j|^2 - 2 q.p_j) ----
        float ax[QPW], ay[QPW], az[QPW], best[QPW];
        int idx[QPW];
        #pragma unroll
        for (int j = 0; j < QPW; ++j) {
            ax[j] = -2.0f * qx[j]; ay[j] = -2.0f * qy[j]; az[j] = -2.0f * qz[j];
            best[j] = 3.4e38f; idx[j] = 0;
        }
        #pragma unroll 4
        for (int k = 0; k < N_PTS / 64; ++k) {
            const int j = lane + (k << 6);
            const float4 P = sp2[j];
            #pragma unroll
            for (int q = 0; q < QPW; ++q) {
                float sd = __builtin_fmaf(P.z, az[q], P.w);
                sd = __builtin_fmaf(P.y, ay[q], sd);
                sd = __builtin_fmaf(P.x, ax[q], sd);
                if (sd < best[q]) { best[q] = sd; idx[q] = j; }  // ascending j: tie->min idx
            }
        }
        #pragma unroll
        for (int off = 32; off; off >>= 1) {
            #pragma unroll
            for (int q = 0; q < QPW; ++q) {
                const float ov = __shfl_xor(best[q], off, 64);
                const int oi = __shfl_xor(idx[q], off, 64);
                if (ov < best[q] || (ov == best[q] && oi < idx[q])) {
                    best[q] = ov; idx[q] = oi;
                }
            }
        }

        // ---- per-wave Kabsch partials (lane 0) -> block row of 16 ----
        __syncthreads();   // protect wred reuse
        if (lane == 0) {
            float Sx = 0, Sy = 0, Sz = 0, Tx = 0, Ty = 0, Tz = 0;
            float m0 = 0, m1 = 0, m2 = 0, m3 = 0, m4 = 0, m5 = 0, m6 = 0, m7 = 0, m8 = 0;
            #pragma unroll
            for (int q = 0; q < QPW; ++q) {
                const float4 M = sp2[idx[q]];
                Sx += qx[q]; Sy += qy[q]; Sz += qz[q];
                Tx += M.x;  Ty += M.y;  Tz += M.z;
                m0 += qx[q] * M.x; m1 += qx[q] * M.y; m2 += qx[q] * M.z;
                m3 += qy[q] * M.x; m4 += qy[q] * M.y; m5 += qy[q] * M.z;
                m6 += qz[q] * M.x; m7 += qz[q] * M.y; m8 += qz[q] * M.z;
            }
            float* r = wred[wave];
            r[0] = Sx; r[1] = Sy; r[2] = Sz;
            r[3] = Tx; r[4] = Ty; r[5] = Tz;
            r[6] = m0; r[7] = m1; r[8] = m2;
            r[9] = m3; r[10] = m4; r[11] = m5;
            r[12] = m6; r[13] = m7; r[14] = m8;
            r[15] = 0.0f;
        }
        __syncthreads();
        if (tid < 16) {
            float v = 0.0f;
            #pragma unroll
            for (int w2 = 0; w2 < NWAVE; ++w2) v += wred[w2][tid];
            afaddf(&acc[(s * 16 + tid) * 8 + (bid & 7)], v);
        }
        WAIT_VM0();   // wave 0: acc adds committed at the coherence point
        if (tid == 0) afaddi(&cnt[(s * 8 + (bid & 7)) * 16], 1);

        if (bid == 0) {
            // ================= solver =================
            if (tid < 8) {   // parallel poll: lane i waits its sub-counter == 32
                while (aloadi(&cnt[(s * 8 + tid) * 16]) < NBLK / 8) {
                    __builtin_amdgcn_s_sleep(2);
                }
            }
            __syncthreads();
            if (tid < 128) rr[tid] = aloadf(&acc[s * 128 + tid]);
            __syncthreads();
            if (tid < 16) {
                float sm = 0.0f;
                #pragma unroll
                for (int c = 0; c < 8; ++c) sm += rr[tid * 8 + c];
                sol[tid] = sm;
            }
            __syncthreads();

            const float S1x = sol[0], S1y = sol[1], S1z = sol[2];
            const float S2x = sol[3], S2y = sol[4], S2z = sol[5];
            const float Mxx = sol[6], Mxy = sol[7], Mxz = sol[8];
            const float Myx = sol[9], Myy = sol[10], Myz = sol[11];
            const float Mzx = sol[12], Mzy = sol[13], Mzz = sol[14];

            const float invN = 1.0f / (float)N_PTS;
            const float c1x = S1x * invN, c1y = S1y * invN, c1z = S1z * invN;
            const float c2x = S2x * invN, c2y = S2y * invN, c2z = S2z * invN;

            const float Sxx = Mxx - S1x * S2x * invN;
            const float Sxy = Mxy - S1x * S2y * invN;
            const float Sxz = Mxz - S1x * S2z * invN;
            const float Syx = Myx - S1y * S2x * invN;
            const float Syy = Myy - S1y * S2y * invN;
            const float Syz = Myz - S1y * S2z * invN;
            const float Szx = Mzx - S1z * S2x * invN;
            const float Szy = Mzy - S1z * S2y * invN;
            const float Szz = Mzz - S1z * S2z * invN;

            const float N00 = Sxx + Syy + Szz;
            const float N01 = Syz - Szy;
            const float N02 = Szx - Sxz;
            const float N03 = Sxy - Syx;
            const float N11 = Sxx - Syy - Szz;
            const float N12 = Sxy + Syx;
            const float N13 = Szx + Sxz;
            const float N22 = -Sxx + Syy - Szz;
            const float N23 = Syz + Szy;
            const float N33 = -Sxx - Syy + Szz;

            const float fro = sqrtf(N00 * N00 + N11 * N11 + N22 * N22 + N33 * N33 +
                                    2.0f * (N01 * N01 + N02 * N02 + N03 * N03 +
                                            N12 * N12 + N13 * N13 + N23 * N23));
            const float sg = fro + 1e-20f;

            float w = 1.0f, x = 0.0f, y = 0.0f, z = 0.0f;
            for (int it = 0; it < POWER_ITERS; ++it) {
                const float r0 = N00 * w + N01 * x + N02 * y + N03 * z + sg * w;
                const float r1 = N01 * w + N11 * x + N12 * y + N13 * z + sg * x;
                const float r2 = N02 * w + N12 * x + N22 * y + N23 * z + sg * y;
                const float r3 = N03 * w + N13 * x + N23 * y + N33 * z + sg * z;
                const float inv = rsqrtf(r0 * r0 + r1 * r1 + r2 * r2 + r3 * r3 + 1e-30f);
                w = r0 * inv; x = r1 * inv; y = r2 * inv; z = r3 * inv;
            }

            const float xx = x * x, yy = y * y, zz = z * z;
            const float xy = x * y, xz = x * z, yz = y * z;
            const float wx = w * x, wy = w * y, wz = w * z;
            const float R00 = 1.0f - 2.0f * (yy + zz), R01 = 2.0f * (xy - wz), R02 = 2.0f * (xz + wy);
            const float R10 = 2.0f * (xy + wz), R11 = 1.0f - 2.0f * (xx + zz), R12 = 2.0f * (yz - wx);
            const float R20 = 2.0f * (xz - wy), R21 = 2.0f * (yz + wx), R22 = 1.0f - 2.0f * (xx + yy);

            const float tx = c2x - (R00 * c1x + R01 * c1y + R02 * c1z);
            const float ty = c2y - (R10 * c1x + R11 * c1y + R12 * c1z);
            const float tz = c2z - (R20 * c1x + R21 * c1y + R22 * c1z);

            // compose totals
            {
                const float nw = w * cqw - x * cqx - y * cqy - z * cqz;
                const float nx = w * cqx + x * cqw + y * cqz - z * cqy;
                const float ny = w * cqy - x * cqz + y * cqw + z * cqx;
                const float nz = w * cqz + x * cqy - y * cqx + z * cqw;
                cqw = nw; cqx = nx; cqy = ny; cqz = nz;
                const float ntx = R00 * ctx + R01 * cty + R02 * ctz + tx;
                const float nty = R10 * ctx + R11 * cty + R12 * ctz + ty;
                const float ntz = R20 * ctx + R21 * cty + R22 * ctz + tz;
                ctx = ntx; cty = nty; ctz = ntz;
            }

            if (!last) {
                if (tid == 0) {
                    bl[0] = R00; bl[1] = R01; bl[2] = R02;
                    bl[3] = R10; bl[4] = R11; bl[5] = R12;
                    bl[6] = R20; bl[7] = R21; bl[8] = R22;
                    bl[9] = tx;  bl[10] = ty; bl[11] = tz;
                }
                __syncthreads();
                if (tid < 192) {                      // 16 replicas x 12 values
                    const int cp = tid / 12, i = tid - cp * 12;
                    afaddf(&rt[(s * 16 + cp) * 12 + i], bl[i]);
                }
                WAIT_VM0();                           // waves 0-2: rt committed
                __syncthreads();
                if (tid < 16) afaddi(&flag[(s * 16 + tid) * 16], 1);

                #pragma unroll
                for (int q = 0; q < QPW; ++q) {
                    const float nx0 = R00 * qx[q] + R01 * qy[q] + R02 * qz[q] + tx;
                    const float ny0 = R10 * qx[q] + R11 * qy[q] + R12 * qz[q] + ty;
                    const float nz0 = R20 * qx[q] + R21 * qy[q] + R22 * qz[q] + tz;
                    qx[q] = nx0; qy[q] = ny0; qz[q] = nz0;
                }
            } else if (tid == 0) {
                // final Kabsch(p1, pc) == composed transform (H = C*Rc^T, C SPD)
                const float fxx = cqx * cqx, fyy = cqy * cqy, fzz = cqz * cqz;
                const float fxy = cqx * cqy, fxz = cqx * cqz, fyz = cqy * cqz;
                const float fwx = cqw * cqx, fwy = cqw * cqy, fwz = cqw * cqz;
                out[0]  = 1.0f - 2.0f * (fyy + fzz);
                out[1]  = 2.0f * (fxy - fwz);
                out[2]  = 2.0f * (fxz + fwy);
                out[3]  = ctx;
                out[4]  = 2.0f * (fxy + fwz);
                out[5]  = 1.0f - 2.0f * (fxx + fzz);
                out[6]  = 2.0f * (fyz - fwx);
                out[7]  = cty;
                out[8]  = 2.0f * (fxz - fwy);
                out[9]  = 2.0f * (fyz + fwx);
                out[10] = 1.0f - 2.0f * (fxx + fyy);
                out[11] = ctz;
            }
        } else if (!last) {
            // ================= spinners =================
            if (tid == 0) {
                while (aloadi(&flag[(s * 16 + (bid & 15)) * 16]) == 0) {
                    __builtin_amdgcn_s_sleep(2);
                }
            }
            __syncthreads();
            if (tid < 12) bl[tid] = aloadf(&rt[(s * 16 + (bid & 15)) * 12 + tid]);
            __syncthreads();
            const float R00 = bl[0], R01 = bl[1], R02 = bl[2];
            const float R10 = bl[3], R11 = bl[4], R12 = bl[5];
            const float R20 = bl[6], R21 = bl[7], R22 = bl[8];
            const float tx = bl[9], ty = bl[10], tz = bl[11];
            #pragma unroll
            for (int q = 0; q < QPW; ++q) {
                const float nx0 = R00 * qx[q] + R01 * qy[q] + R02 * qz[q] + tx;
                const float ny0 = R10 * qx[q] + R11 * qy[q] + R12 * qz[q] + ty;
                const float nz0 = R20 * qx[q] + R21 * qy[q] + R22 * qz[q] + tz;
                qx[q] = nx0; qy[q] = ny0; qz[q] = nz0;
            }
        }
    }
}

extern "C" void kernel_launch(void* const* d_in, const int* in_sizes, int n_in,
                              void* d_out, int out_size, void* d_ws, size_t ws_size,
                              hipStream_t stream) {
    const float* p1 = (const float*)d_in[0];
    const float* p2 = (const float*)d_in[1];
    float* out = (float*)d_out;
    int* ctrl = (int*)d_ws;

    hipMemsetAsync(ctrl, 0, CTRL_ELEMS * sizeof(int), stream);

    void* args[] = {(void*)&p1, (void*)&p2, (void*)&ctrl, (void*)&out};
    hipLaunchCooperativeKernel((const void*)icp_pk, dim3(NBLK), dim3(BS), args, 0, stream);
}

// Round 6
// 216.520 us; speedup vs baseline: 2.6519x; 1.1016x over previous
//
#include <hip/hip_runtime.h>

#define N_PTS 4096
#define ICP_STEPS 10
#define NBLK 256          // 1 block/CU (cooperative launch guarantees co-residency)
#define BS 256            // 4 waves/block; 4 queries per wave -> 16 queries/block
#define NWAVE (BS / 64)
#define QPW 4
#define POWER_ITERS 16
#define NCOL 8            // replica columns; block reads column bid&7
#define NSLOT 18          // 15 data + checksum + weighted checksum + count
#define FP_SCALE 16777216.0   // 2^24 fixed point
#define FP_INV   (1.0 / 16777216.0)

// acc: [ICP_STEPS][NCOL][NSLOT] u64, zeroed by hipMemsetAsync each launch.
#define ACC_U64S (ICP_STEPS * NCOL * NSLOT)   // 1440 u64 = 11520 B

__device__ __forceinline__ unsigned long long au64_add(unsigned long long* p,
                                                       unsigned long long v) {
    return __hip_atomic_fetch_add(p, v, __ATOMIC_RELAXED, __HIP_MEMORY_SCOPE_AGENT);
}

__global__ __launch_bounds__(BS, 1) void icp_pk(const float* __restrict__ p1,
                                                const float* __restrict__ p2,
                                                unsigned long long* __restrict__ acc,
                                                float* __restrict__ out) {
    __shared__ __align__(16) float4 sp2[N_PTS];   // 64 KB {x,y,z,|p|^2}
    __shared__ float wred[NWAVE][16];
    __shared__ long long sred[NSLOT];
    __shared__ float sH[16];

    const int tid = threadIdx.x;
    const int bid = blockIdx.x;
    const int wave = tid >> 6;
    const int lane = tid & 63;

    // ---- stage p2 -> LDS once ----
    for (int p = tid; p < N_PTS; p += BS) {
        const float x = p2[3 * p + 0];
        const float y = p2[3 * p + 1];
        const float z = p2[3 * p + 2];
        sp2[p] = make_float4(x, y, z, x * x + y * y + z * z);
    }

    // ---- owned queries: 16/block, 4/wave (all lanes track the same 4) ----
    const int qb = bid * 16 + wave * QPW;
    float qx[QPW], qy[QPW], qz[QPW];
    #pragma unroll
    for (int j = 0; j < QPW; ++j) {
        qx[j] = p1[3 * (qb + j) + 0];
        qy[j] = p1[3 * (qb + j) + 1];
        qz[j] = p1[3 * (qb + j) + 2];
    }

    // composed transform (tracked identically by all threads; bid0 writes out)
    float cqw = 1.0f, cqx = 0.0f, cqy = 0.0f, cqz = 0.0f;
    float ctx = 0.0f, cty = 0.0f, ctz = 0.0f;

    __syncthreads();

    for (int s = 0; s < ICP_STEPS; ++s) {
        // ---- 1-NN for 4 queries: argmin_j (|p_j|^2 - 2 q.p_j) ----
        float ax[QPW], ay[QPW], az[QPW], best[QPW];
        int idx[QPW];
        #pragma unroll
        for (int j = 0; j < QPW; ++j) {
            ax[j] = -2.0f * qx[j]; ay[j] = -2.0f * qy[j]; az[j] = -2.0f * qz[j];
            best[j] = 3.4e38f; idx[j] = 0;
        }
        #pragma unroll 8
        for (int k = 0; k < N_PTS / 64; ++k) {
            const int j = lane + (k << 6);
            const float4 P = sp2[j];
            #pragma unroll
            for (int q = 0; q < QPW; ++q) {
                float sd = __builtin_fmaf(P.z, az[q], P.w);
                sd = __builtin_fmaf(P.y, ay[q], sd);
                sd = __builtin_fmaf(P.x, ax[q], sd);
                if (sd < best[q]) { best[q] = sd; idx[q] = j; }  // tie -> min idx
            }
        }
        #pragma unroll
        for (int off = 32; off; off >>= 1) {
            #pragma unroll
            for (int q = 0; q < QPW; ++q) {
                const float ov = __shfl_xor(best[q], off, 64);
                const int oi = __shfl_xor(idx[q], off, 64);
                if (ov < best[q] || (ov == best[q] && oi < idx[q])) {
                    best[q] = ov; idx[q] = oi;
                }
            }
        }

        // ---- per-wave Kabsch partials (lane 0) ----
        __syncthreads();
        if (lane == 0) {
            float Sx = 0, Sy = 0, Sz = 0, Tx = 0, Ty = 0, Tz = 0;
            float m0 = 0, m1 = 0, m2 = 0, m3 = 0, m4 = 0, m5 = 0, m6 = 0, m7 = 0, m8 = 0;
            #pragma unroll
            for (int q = 0; q < QPW; ++q) {
                const float4 M = sp2[idx[q]];
                Sx += qx[q]; Sy += qy[q]; Sz += qz[q];
                Tx += M.x;  Ty += M.y;  Tz += M.z;
                m0 += qx[q] * M.x; m1 += qx[q] * M.y; m2 += qx[q] * M.z;
                m3 += qy[q] * M.x; m4 += qy[q] * M.y; m5 += qy[q] * M.z;
                m6 += qz[q] * M.x; m7 += qz[q] * M.y; m8 += qz[q] * M.z;
            }
            float* r = wred[wave];
            r[0] = Sx; r[1] = Sy; r[2] = Sz;
            r[3] = Tx; r[4] = Ty; r[5] = Tz;
            r[6] = m0; r[7] = m1; r[8] = m2;
            r[9] = m3; r[10] = m4; r[11] = m5;
            r[12] = m6; r[13] = m7; r[14] = m8;
            r[15] = 0.0f;
        }
        __syncthreads();
        // block sums -> fixed-point int64
        if (tid < 15) {
            float bs = 0.0f;
            #pragma unroll
            for (int w2 = 0; w2 < NWAVE; ++w2) bs += wred[w2][tid];
            sred[tid] = llrint((double)bs * FP_SCALE);
        }
        __syncthreads();
        if (tid == 0) {
            long long cs1 = 0, cs2 = 0;
            #pragma unroll
            for (int k = 0; k < 15; ++k) {
                cs1 += sred[k];
                cs2 += (long long)(k + 1) * sred[k];
            }
            sred[15] = cs1; sred[16] = cs2; sred[17] = 1;
        }
        __syncthreads();

        // ---- one parallel volley: 18 slots x 8 columns, fire-and-forget ----
        unsigned long long* sacc = acc + (size_t)s * (NCOL * NSLOT);
        if (tid < NCOL * NSLOT) {   // 144 threads (waves 0-2)
            const int col = tid / NSLOT, slot = tid - col * NSLOT;
            au64_add(&sacc[col * NSLOT + slot], (unsigned long long)sred[slot]);
        }

        // ---- wave 0: verified read of own column (checksummed, exact) ----
        if (wave == 0) {
            unsigned long long* mycol = sacc + (bid & (NCOL - 1)) * NSLOT;
            long long v;
            bool ok;
            do {
                long long x = 0;
                if (lane < NSLOT)
                    x = (long long)au64_add(&mycol[lane], 0ull);
                long long s1 = (lane < 15) ? x : 0;
                long long s2 = (lane < 15) ? (long long)(lane + 1) * x : 0;
                #pragma unroll
                for (int off = 32; off; off >>= 1) {
                    s1 += __shfl_xor(s1, off, 64);
                    s2 += __shfl_xor(s2, off, 64);
                }
                const long long cs1 = __shfl(x, 15, 64);
                const long long cs2 = __shfl(x, 16, 64);
                const long long cnt = __shfl(x, 17, 64);
                ok = (cnt == (long long)NBLK) && (s1 == cs1) && (s2 == cs2);
                v = x;
            } while (!ok);
            if (lane < 15) sH[lane] = (float)((double)v * FP_INV);
        }
        __syncthreads();

        // ---- every block solves Horn redundantly (identical int inputs) ----
        const float S1x = sH[0], S1y = sH[1], S1z = sH[2];
        const float S2x = sH[3], S2y = sH[4], S2z = sH[5];
        const float Mxx = sH[6], Mxy = sH[7], Mxz = sH[8];
        const float Myx = sH[9], Myy = sH[10], Myz = sH[11];
        const float Mzx = sH[12], Mzy = sH[13], Mzz = sH[14];

        const float invN = 1.0f / (float)N_PTS;
        const float c1x = S1x * invN, c1y = S1y * invN, c1z = S1z * invN;
        const float c2x = S2x * invN, c2y = S2y * invN, c2z = S2z * invN;

        const float Sxx = Mxx - S1x * S2x * invN;
        const float Sxy = Mxy - S1x * S2y * invN;
        const float Sxz = Mxz - S1x * S2z * invN;
        const float Syx = Myx - S1y * S2x * invN;
        const float Syy = Myy - S1y * S2y * invN;
        const float Syz = Myz - S1y * S2z * invN;
        const float Szx = Mzx - S1z * S2x * invN;
        const float Szy = Mzy - S1z * S2y * invN;
        const float Szz = Mzz - S1z * S2z * invN;

        const float N00 = Sxx + Syy + Szz;
        const float N01 = Syz - Szy;
        const float N02 = Szx - Sxz;
        const float N03 = Sxy - Syx;
        const float N11 = Sxx - Syy - Szz;
        const float N12 = Sxy + Syx;
        const float N13 = Szx + Sxz;
        const float N22 = -Sxx + Syy - Szz;
        const float N23 = Syz + Szy;
        const float N33 = -Sxx - Syy + Szz;

        const float fro = sqrtf(N00 * N00 + N11 * N11 + N22 * N22 + N33 * N33 +
                                2.0f * (N01 * N01 + N02 * N02 + N03 * N03 +
                                        N12 * N12 + N13 * N13 + N23 * N23));
        const float sg = fro + 1e-20f;

        float w = 1.0f, x = 0.0f, y = 0.0f, z = 0.0f;
        for (int it = 0; it < POWER_ITERS; ++it) {
            const float r0 = N00 * w + N01 * x + N02 * y + N03 * z + sg * w;
            const float r1 = N01 * w + N11 * x + N12 * y + N13 * z + sg * x;
            const float r2 = N02 * w + N12 * x + N22 * y + N23 * z + sg * y;
            const float r3 = N03 * w + N13 * x + N23 * y + N33 * z + sg * z;
            const float inv = rsqrtf(r0 * r0 + r1 * r1 + r2 * r2 + r3 * r3 + 1e-30f);
            w = r0 * inv; x = r1 * inv; y = r2 * inv; z = r3 * inv;
        }

        const float xx = x * x, yy = y * y, zz = z * z;
        const float xy = x * y, xz = x * z, yz = y * z;
        const float wx = w * x, wy = w * y, wz = w * z;
        const float R00 = 1.0f - 2.0f * (yy + zz), R01 = 2.0f * (xy - wz), R02 = 2.0f * (xz + wy);
        const float R10 = 2.0f * (xy + wz), R11 = 1.0f - 2.0f * (xx + zz), R12 = 2.0f * (yz - wx);
        const float R20 = 2.0f * (xz - wy), R21 = 2.0f * (yz + wx), R22 = 1.0f - 2.0f * (xx + yy);

        const float tx = c2x - (R00 * c1x + R01 * c1y + R02 * c1z);
        const float ty = c2y - (R10 * c1x + R11 * c1y + R12 * c1z);
        const float tz = c2z - (R20 * c1x + R21 * c1y + R22 * c1z);

        // transform owned queries
        #pragma unroll
        for (int q = 0; q < QPW; ++q) {
            const float nx0 = R00 * qx[q] + R01 * qy[q] + R02 * qz[q] + tx;
            const float ny0 = R10 * qx[q] + R11 * qy[q] + R12 * qz[q] + ty;
            const float nz0 = R20 * qx[q] + R21 * qy[q] + R22 * qz[q] + tz;
            qx[q] = nx0; qy[q] = ny0; qz[q] = nz0;
        }

        // compose totals: q_tot = q_step (*) q_tot ; t_tot = R_step t_tot + t_step
        {
            const float nw = w * cqw - x * cqx - y * cqy - z * cqz;
            const float nx = w * cqx + x * cqw + y * cqz - z * cqy;
            const float ny = w * cqy - x * cqz + y * cqw + z * cqx;
            const float nz = w * cqz + x * cqy - y * cqx + z * cqw;
            cqw = nw; cqx = nx; cqy = ny; cqz = nz;
            const float ntx = R00 * ctx + R01 * cty + R02 * ctz + tx;
            const float nty = R10 * ctx + R11 * cty + R12 * ctz + ty;
            const float ntz = R20 * ctx + R21 * cty + R22 * ctz + tz;
            ctx = ntx; cty = nty; ctz = ntz;
        }
    }

    // final Kabsch(p1, pc) == composed transform (exact; H = C*Rc^T, C SPD)
    if (bid == 0 && tid == 0) {
        const float fxx = cqx * cqx, fyy = cqy * cqy, fzz = cqz * cqz;
        const float fxy = cqx * cqy, fxz = cqx * cqz, fyz = cqy * cqz;
        const float fwx = cqw * cqx, fwy = cqw * cqy, fwz = cqw * cqz;
        out[0]  = 1.0f - 2.0f * (fyy + fzz);
        out[1]  = 2.0f * (fxy - fwz);
        out[2]  = 2.0f * (fxz + fwy);
        out[3]  = ctx;
        out[4]  = 2.0f * (fxy + fwz);
        out[5]  = 1.0f - 2.0f * (fxx + fzz);
        out[6]  = 2.0f * (fyz - fwx);
        out[7]  = cty;
        out[8]  = 2.0f * (fxz - fwy);
        out[9]  = 2.0f * (fyz + fwx);
        out[10] = 1.0f - 2.0f * (fxx + fyy);
        out[11] = ctz;
    }
}

extern "C" void kernel_launch(void* const* d_in, const int* in_sizes, int n_in,
                              void* d_out, int out_size, void* d_ws, size_t ws_size,
                              hipStream_t stream) {
    const float* p1 = (const float*)d_in[0];
    const float* p2 = (const float*)d_in[1];
    float* out = (float*)d_out;
    unsigned long long* acc = (unsigned long long*)d_ws;

    hipMemsetAsync(acc, 0, ACC_U64S * sizeof(unsigned long long), stream);

    void* args[] = {(void*)&p1, (void*)&p2, (void*)&acc, (void*)&out};
    hipLaunchCooperativeKernel((const void*)icp_pk, dim3(NBLK), dim3(BS), args, 0, stream);
}